// Round 7
// baseline (286.187 us; speedup 1.0000x reference)
//
#include <hip/hip_runtime.h>
#include <stdint.h>

#define TEMP_ 0.75f
#define EPS_ 1e-6f

typedef __attribute__((ext_vector_type(8))) short bf16x8;
typedef __attribute__((ext_vector_type(4))) float f32x4;

typedef __attribute__((address_space(1))) void gvoid_t;
typedef __attribute__((address_space(3))) void lvoid_t;

__device__ __forceinline__ void async_ld16(const void* g, void* l) {
  __builtin_amdgcn_global_load_lds((gvoid_t*)g, (lvoid_t*)l, 16, 0, 0);
}

__device__ __forceinline__ float b2f(ushort u) {
  return __builtin_bit_cast(float, (uint32_t)u << 16);
}
__device__ __forceinline__ ushort f2b(float f) {
  uint32_t x = __builtin_bit_cast(uint32_t, f);
  x += 0x7fffu + ((x >> 16) & 1u);
  return (ushort)(x >> 16);
}

// ------------------------------------------------------- prep_x: fp32 x -> bf16 xb + fp32 partial bucket sums
// grid 1024: block = (bu, oct of 8 pos). xsum8[bu*8+oct][1024].
__global__ __launch_bounds__(256) void prep_x(
    const float* __restrict__ x, ushort* __restrict__ xb, float* __restrict__ xsum8) {
  const int blk = blockIdx.x;
  const int bu = blk >> 3, oct = blk & 7;
  const int b = bu >> 6, u = bu & 63;
  const int c = threadIdx.x * 4;
  const float* src = x + ((size_t)(b * 4096 + u * 64 + oct * 8)) * 1024 + c;
  ushort* dst = xb + ((size_t)(b * 4096 + u * 64 + oct * 8)) * 1024 + c;
  float s0 = 0.f, s1 = 0.f, s2 = 0.f, s3 = 0.f;
  #pragma unroll
  for (int pos = 0; pos < 8; pos++) {
    float4 v = *(const float4*)(src + (size_t)pos * 1024);
    s0 += v.x; s1 += v.y; s2 += v.z; s3 += v.w;
    ushort4 o;
    o.x = f2b(v.x); o.y = f2b(v.y); o.z = f2b(v.z); o.w = f2b(v.w);
    *(ushort4*)(dst + (size_t)pos * 1024) = o;
  }
  float4 sv = {s0, s1, s2, s3};
  *(float4*)&xsum8[(size_t)blk * 1024 + c] = sv;
}

// ------------------------------------------------------- transpose + fp32->bf16
__global__ __launch_bounds__(256) void transpose_f2b(
    const float* __restrict__ src, ushort* __restrict__ dst, int R, int C) {
  __shared__ float tile[32][33];
  int bx = blockIdx.x * 32;
  int by = blockIdx.y * 32;
  int tx = threadIdx.x & 31, ty = threadIdx.x >> 5;  // 32 x 8
  #pragma unroll
  for (int i = 0; i < 32; i += 8)
    tile[ty + i][tx] = src[(size_t)(by + ty + i) * C + bx + tx];
  __syncthreads();
  #pragma unroll
  for (int i = 0; i < 32; i += 8)
    dst[(size_t)(bx + ty + i) * R + by + tx] = f2b(tile[tx][ty + i]);
}

// ------------------------------------------------------- sx partial: split-K over 8 chunks
// SXP[kc*128 + bu][n]  (n in [0,2048))
__global__ __launch_bounds__(256) void sx_gemm_partial(
    const float* __restrict__ xsum8, const float* __restrict__ wqkv,
    float* __restrict__ SXP) {
  __shared__ float xs[128 * 8];  // k-major: xs[k*8 + r]
  const int cb = blockIdx.x;  // 8 colblocks of 256 n
  const int rt = blockIdx.y;  // 16 rowtiles of 8 bu
  const int kc = blockIdx.z;  // 8 k-chunks of 128
  const int tid = threadIdx.x;
  for (int idx = tid; idx < 1024; idx += 256) {
    int k = idx >> 3, r = idx & 7;
    int bu = rt * 8 + r;
    int kk = kc * 128 + k;
    float s = 0.f;
    #pragma unroll
    for (int o = 0; o < 8; o++)
      s += xsum8[(size_t)(bu * 8 + o) * 1024 + kk];
    xs[idx] = s;
  }
  __syncthreads();
  const int n = cb * 256 + tid;
  float acc[8];
  #pragma unroll
  for (int r = 0; r < 8; r++) acc[r] = 0.f;
  for (int k = 0; k < 128; k++) {
    float w = wqkv[(size_t)(kc * 128 + k) * 3072 + n];
    float4 a0 = *(const float4*)&xs[k * 8];
    float4 a1 = *(const float4*)&xs[k * 8 + 4];
    acc[0] += a0.x * w; acc[1] += a0.y * w; acc[2] += a0.z * w; acc[3] += a0.w * w;
    acc[4] += a1.x * w; acc[5] += a1.y * w; acc[6] += a1.z * w; acc[7] += a1.w * w;
  }
  #pragma unroll
  for (int r = 0; r < 8; r++)
    SXP[(size_t)(kc * 128 + rt * 8 + r) * 2048 + n] = acc[r];
}

// ------------------------------------------------------- sx reduce: fixed-order sum + scatter
// SX layout: [bh][e2(256)][u(64)]
__global__ __launch_bounds__(256) void sx_reduce(
    const float* __restrict__ SXP, float* __restrict__ SX) {
  const int bu = blockIdx.y;
  const int n = blockIdx.x * 256 + threadIdx.x;
  float s = 0.f;
  #pragma unroll
  for (int kc = 0; kc < 8; kc++)
    s += SXP[(size_t)(kc * 128 + bu) * 2048 + n];
  const int head = (n >> 7) & 7;
  const int e2 = ((n >> 10) << 7) | (n & 127);
  const int b = bu >> 6, u = bu & 63;
  SX[((size_t)((b * 8 + head) * 256) + e2) * 64 + u] = s;
}

// ------------------------------------------------------- sortnet + sinkhorn + top1 (fp32, LDS-staged)
__global__ __launch_bounds__(256) void sortnet_sinkhorn(
    const float* __restrict__ SX, const float* __restrict__ sortw,
    const float* __restrict__ gum, int* __restrict__ idxArr,
    float* __restrict__ wgtArr) {
  __shared__ float sxl[64 * 64];  // chunk: [e][u]  16 KB
  __shared__ float wl[64 * 64];   // chunk: [e][c]  16 KB
  __shared__ float rr[64 * 65];   // 16.6 KB
  __shared__ float redA[256];
  __shared__ float redB[256];
  __shared__ int redi[256];
  const int bh = blockIdx.x, tid = threadIdx.x, head = bh & 7;
  const int ui = tid & 15, ci = tid >> 4;  // 4x4 tile position

  float acc[4][4];
  #pragma unroll
  for (int i = 0; i < 4; i++)
    #pragma unroll
    for (int j = 0; j < 4; j++) acc[i][j] = 0.f;

  const f32x4* SX4 = (const f32x4*)(SX + (size_t)bh * 16384);
  const f32x4* W4 = (const f32x4*)(sortw + (size_t)head * 16384);
  f32x4* sxl4 = (f32x4*)sxl;
  f32x4* wl4 = (f32x4*)wl;

  #pragma unroll 1
  for (int ch = 0; ch < 4; ch++) {
    __syncthreads();
    #pragma unroll 1
    for (int g = tid; g < 1024; g += 256) {
      sxl4[g] = SX4[ch * 1024 + g];
      wl4[g] = W4[ch * 1024 + g];
    }
    __syncthreads();
    #pragma unroll 2
    for (int e = 0; e < 64; e++) {
      f32x4 a = sxl4[e * 16 + ui];
      f32x4 w = wl4[e * 16 + ci];
      #pragma unroll
      for (int i = 0; i < 4; i++)
        #pragma unroll
        for (int j = 0; j < 4; j++) acc[i][j] += a[i] * w[j];
    }
  }

  // leaky relu + gumbel + log -> rr
  #pragma unroll
  for (int i = 0; i < 4; i++)
    #pragma unroll
    for (int j = 0; j < 4; j++) {
      int u = ui * 4 + i, c = ci * 4 + j;
      float dot = acc[i][j];
      float r0 = dot > 0.f ? dot : 0.01f * dot;
      float gu = gum[(size_t)bh * 4096 + u * 64 + c];
      float inner = -logf(gu + EPS_) + EPS_;
      float g = -logf(fmaxf(inner, 1e-38f));
      rr[u * 65 + c] = (logf(fmaxf(r0 + EPS_, EPS_)) + g) / TEMP_;
    }
  __syncthreads();

  const int su = tid & 63, sq = tid >> 6;
  #pragma unroll 1
  for (int it = 0; it < 5; it++) {
    {  // row norm (axis c)
      float pm = -1e30f;
      #pragma unroll
      for (int j = 0; j < 16; j++) pm = fmaxf(pm, rr[su * 65 + sq * 16 + j]);
      redA[sq * 64 + su] = pm;
      __syncthreads();
      float m = fmaxf(fmaxf(redA[su], redA[64 + su]), fmaxf(redA[128 + su], redA[192 + su]));
      float ps = 0.f;
      #pragma unroll
      for (int j = 0; j < 16; j++) ps += expf(rr[su * 65 + sq * 16 + j] - m);
      redB[sq * 64 + su] = ps;
      __syncthreads();
      float l = m + logf(redB[su] + redB[64 + su] + redB[128 + su] + redB[192 + su]);
      #pragma unroll
      for (int j = 0; j < 16; j++) rr[su * 65 + sq * 16 + j] -= l;
      __syncthreads();
    }
    {  // col norm (axis u)
      float pm = -1e30f;
      #pragma unroll
      for (int j = 0; j < 16; j++) pm = fmaxf(pm, rr[(sq * 16 + j) * 65 + su]);
      redA[sq * 64 + su] = pm;
      __syncthreads();
      float m = fmaxf(fmaxf(redA[su], redA[64 + su]), fmaxf(redA[128 + su], redA[192 + su]));
      float ps = 0.f;
      #pragma unroll
      for (int j = 0; j < 16; j++) ps += expf(rr[(sq * 16 + j) * 65 + su] - m);
      redB[sq * 64 + su] = ps;
      __syncthreads();
      float l = m + logf(redB[su] + redB[64 + su] + redB[128 + su] + redB[192 + su]);
      #pragma unroll
      for (int j = 0; j < 16; j++) rr[(sq * 16 + j) * 65 + su] -= l;
      __syncthreads();
    }
  }

  {  // first-max argmax over cols (np semantics), 4-way parallel
    float pv = -1e30f;
    int pi = 0;
    #pragma unroll
    for (int j = 0; j < 16; j++) {
      float v = rr[su * 65 + sq * 16 + j];
      if (v > pv) { pv = v; pi = sq * 16 + j; }
    }
    redA[sq * 64 + su] = pv;
    redi[sq * 64 + su] = pi;
    __syncthreads();
    if (tid < 64) {
      float best = -1e30f;
      int bi = 0;
      #pragma unroll
      for (int q = 0; q < 4; q++) {
        float v = redA[q * 64 + tid];
        if (v > best) { best = v; bi = redi[q * 64 + tid]; }
      }
      idxArr[bh * 64 + tid] = bi;
      wgtArr[bh * 64 + tid] = expf(fminf(best, 80.f));
    }
  }
}

// ------------------------------------------------------- GEMM (m97 style), bf16 MFMA
// LDS XOR-swizzle: global (row, chunk c) stored at position c ^ (row&3).
// Staging picks chunk = (lane&3) ^ ((lane>>2)&3); reads use quad ^ (l16&3).
__global__ __launch_bounds__(256, 2) void gemm_bt(
    const ushort* __restrict__ A, const ushort* __restrict__ BT,
    int M, int N, int K, int mode,
    const float* __restrict__ bias, float* __restrict__ Cout,
    ushort* __restrict__ Qb, ushort* __restrict__ Kb, ushort* __restrict__ VT) {
  __shared__ ushort As[128 * 32];
  __shared__ ushort Bs[128 * 32];
  const int tid = threadIdx.x;
  const int wave = tid >> 6, lane = tid & 63;
  const int quad = lane >> 4, l16 = lane & 15;
  const int m0 = blockIdx.y * 128, n0 = blockIdx.x * 128;
  const int wm = (wave >> 1) * 64, wn = (wave & 1) * 64;

  f32x4 acc[4][4];
  #pragma unroll
  for (int i = 0; i < 4; i++)
    #pragma unroll
    for (int j = 0; j < 4; j++) acc[i][j] = (f32x4){0.f, 0.f, 0.f, 0.f};

  const int srow = wave * 32 + (lane >> 2);
  const int schunk = (((lane & 3) ^ ((lane >> 2) & 3))) * 8;  // XOR swizzle
  const int rsw = (quad ^ (l16 & 3)) * 8;                     // read-side swizzle

  for (int k0 = 0; k0 < K; k0 += 32) {
    __syncthreads();
    {
      const ushort* gA0 = A + (uint64_t)(m0 + srow) * K + k0 + schunk;
      const ushort* gB0 = BT + (uint64_t)(n0 + srow) * K + k0 + schunk;
      ushort* lA = (ushort*)As + (wave * 32) * 32;
      ushort* lB = (ushort*)Bs + (wave * 32) * 32;
      async_ld16(gA0, lA);
      async_ld16(gA0 + (uint64_t)16 * K, lA + 16 * 32);
      async_ld16(gB0, lB);
      async_ld16(gB0 + (uint64_t)16 * K, lB + 16 * 32);
    }
    __syncthreads();
    bf16x8 af[4], bfr[4];
    #pragma unroll
    for (int mt = 0; mt < 4; mt++)
      af[mt] = *(const bf16x8*)&As[(wm + mt * 16 + l16) * 32 + rsw];
    #pragma unroll
    for (int nt = 0; nt < 4; nt++)
      bfr[nt] = *(const bf16x8*)&Bs[(wn + nt * 16 + l16) * 32 + rsw];
    #pragma unroll
    for (int mt = 0; mt < 4; mt++)
      #pragma unroll
      for (int nt = 0; nt < 4; nt++)
        acc[mt][nt] = __builtin_amdgcn_mfma_f32_16x16x32_bf16(af[mt], bfr[nt], acc[mt][nt], 0, 0, 0);
  }

  if (mode == 0) {
    #pragma unroll
    for (int mt = 0; mt < 4; mt++) {
      int row = m0 + wm + mt * 16 + quad * 4;
      #pragma unroll
      for (int nt = 0; nt < 4; nt++) {
        int col = n0 + wn + nt * 16 + l16;
        float bv = bias[col];
        #pragma unroll
        for (int r = 0; r < 4; r++)
          Cout[(uint64_t)(row + r) * N + col] = acc[mt][nt][r] + bv;
      }
    }
  } else {
    int which = blockIdx.x >> 3;  // 0=q,1=k,2=v  (n0 multiple of 128)
    int head = blockIdx.x & 7;
    #pragma unroll
    for (int mt = 0; mt < 4; mt++) {
      int mrow = m0 + wm + mt * 16 + quad * 4;
      int bidx = mrow >> 12;
      int ttok = mrow & 4095;
      int u = ttok >> 6, pos = ttok & 63;
      int bh = bidx * 8 + head;
      #pragma unroll
      for (int nt = 0; nt < 4; nt++) {
        int e = wn + nt * 16 + l16;
        if (which == 2) {
          ushort4 pk;
          pk.x = f2b(acc[mt][nt][0]);
          pk.y = f2b(acc[mt][nt][1]);
          pk.z = f2b(acc[mt][nt][2]);
          pk.w = f2b(acc[mt][nt][3]);
          *(ushort4*)&VT[((uint64_t)(bh * 64 + u) * 128 + e) * 64 + pos] = pk;
        } else {
          ushort* dst = (which == 0) ? Qb : Kb;
          #pragma unroll
          for (int r = 0; r < 4; r++)
            dst[((uint64_t)(bh * 64 + u) * 64 + pos + r) * 128 + e] = f2b(acc[mt][nt][r]);
        }
      }
    }
  }
}

// ------------------------------------------------------- bucketed attention
#define KSTR 136
__global__ __launch_bounds__(256) void attn_kernel(
    const ushort* __restrict__ Qb, const ushort* __restrict__ Kb,
    const ushort* __restrict__ VT, const int* __restrict__ idxArr,
    const float* __restrict__ wgtArr, ushort* __restrict__ attn_out) {
  __shared__ ushort Qs[64 * KSTR];   // Q, later P
  __shared__ ushort Ks[128 * KSTR];  // K2[j][e], later V2^T[e][j]
  const int blk = blockIdx.x;
  const int u = blk & 63, bh = blk >> 6;
  const int tid = threadIdx.x, wave = tid >> 6, lane = tid & 63;
  const int quad = lane >> 4, l16 = lane & 15;
  const int vu = idxArr[bh * 64 + u] & 63;
  const float w = wgtArr[bh * 64 + u];

  const ushort* Qsrc = Qb + (uint64_t)(bh * 64 + u) * 8192;
  const ushort* Ksrc0 = Kb + (uint64_t)(bh * 64 + vu) * 8192;
  const ushort* Ksrc1 = Kb + (uint64_t)(bh * 64 + u) * 8192;
  const ushort* Vsrc0 = VT + (uint64_t)(bh * 64 + vu) * 8192;
  const ushort* Vsrc1 = VT + (uint64_t)(bh * 64 + u) * 8192;

  for (int g = tid; g < 64 * 16; g += 256) {
    int eb = g & 15, p = g >> 4;
    *(bf16x8*)&Qs[p * KSTR + eb * 8] = *(const bf16x8*)&Qsrc[p * 128 + eb * 8];
  }
  for (int g = tid; g < 128 * 16; g += 256) {
    int eb = g & 15, j = g >> 4;
    const ushort* s = (j < 64) ? &Ksrc0[j * 128 + eb * 8] : &Ksrc1[(j - 64) * 128 + eb * 8];
    *(bf16x8*)&Ks[j * KSTR + eb * 8] = *(const bf16x8*)s;
  }
  __syncthreads();

  f32x4 S[8];
  #pragma unroll
  for (int nt = 0; nt < 8; nt++) S[nt] = (f32x4){0.f, 0.f, 0.f, 0.f};
  #pragma unroll
  for (int kk = 0; kk < 4; kk++) {
    bf16x8 aq = *(const bf16x8*)&Qs[(wave * 16 + l16) * KSTR + kk * 32 + quad * 8];
    #pragma unroll
    for (int nt = 0; nt < 8; nt++) {
      bf16x8 bk = *(const bf16x8*)&Ks[(nt * 16 + l16) * KSTR + kk * 32 + quad * 8];
      S[nt] = __builtin_amdgcn_mfma_f32_16x16x32_bf16(aq, bk, S[nt], 0, 0, 0);
    }
  }
  __syncthreads();  // all waves done reading K2

  // stage V2^T into Ks
  for (int g = tid; g < 128 * 16; g += 256) {
    int jb = g & 15, e = g >> 4;
    const ushort* s = (jb < 8) ? &Vsrc0[e * 64 + jb * 8] : &Vsrc1[e * 64 + (jb - 8) * 8];
    *(bf16x8*)&Ks[e * KSTR + jb * 8] = *(const bf16x8*)s;
  }

  const float scale = 0.03125f;  // (d=1024)^-0.5
  float rowmax[4] = {-1e30f, -1e30f, -1e30f, -1e30f};
  #pragma unroll
  for (int nt = 0; nt < 8; nt++) {
    float cs = scale * ((nt < 4) ? w : 1.0f);
    #pragma unroll
    for (int r = 0; r < 4; r++) {
      S[nt][r] *= cs;
      rowmax[r] = fmaxf(rowmax[r], S[nt][r]);
    }
  }
  #pragma unroll
  for (int off = 1; off < 16; off <<= 1)
    #pragma unroll
    for (int r = 0; r < 4; r++)
      rowmax[r] = fmaxf(rowmax[r], __shfl_xor(rowmax[r], off, 64));
  float rowsum[4] = {0.f, 0.f, 0.f, 0.f};
  #pragma unroll
  for (int nt = 0; nt < 8; nt++)
    #pragma unroll
    for (int r = 0; r < 4; r++) {
      float p = expf(S[nt][r] - rowmax[r]);
      S[nt][r] = p;
      rowsum[r] += p;
    }
  #pragma unroll
  for (int off = 1; off < 16; off <<= 1)
    #pragma unroll
    for (int r = 0; r < 4; r++)
      rowsum[r] += __shfl_xor(rowsum[r], off, 64);
  float rinv[4];
  #pragma unroll
  for (int r = 0; r < 4; r++) rinv[r] = 1.0f / rowsum[r];

  #pragma unroll
  for (int nt = 0; nt < 8; nt++)
    #pragma unroll
    for (int r = 0; r < 4; r++) {
      float pv = S[nt][r] * rinv[r] * ((nt < 4) ? w : 1.0f);
      Qs[(wave * 16 + quad * 4 + r) * KSTR + nt * 16 + l16] = f2b(pv);
    }
  __syncthreads();  // V2^T staged

  f32x4 O[8];
  #pragma unroll
  for (int nt = 0; nt < 8; nt++) O[nt] = (f32x4){0.f, 0.f, 0.f, 0.f};
  #pragma unroll
  for (int kk = 0; kk < 4; kk++) {
    bf16x8 ap = *(const bf16x8*)&Qs[(wave * 16 + l16) * KSTR + kk * 32 + quad * 8];
    #pragma unroll
    for (int nt = 0; nt < 8; nt++) {
      bf16x8 bv = *(const bf16x8*)&Ks[(nt * 16 + l16) * KSTR + kk * 32 + quad * 8];
      O[nt] = __builtin_amdgcn_mfma_f32_16x16x32_bf16(ap, bv, O[nt], 0, 0, 0);
    }
  }

  const int bidx = bh >> 3, head = bh & 7;
  uint64_t rowbase =
      (uint64_t)(bidx * 4096 + u * 64 + wave * 16 + quad * 4) * 1024 + head * 128;
  #pragma unroll
  for (int nt = 0; nt < 8; nt++)
    #pragma unroll
    for (int r = 0; r < 4; r++)
      attn_out[rowbase + (uint64_t)r * 1024 + nt * 16 + l16] = f2b(O[nt][r]);
}

// ---------------------------------------------------------------- launch
extern "C" void kernel_launch(void* const* d_in, const int* in_sizes, int n_in,
                              void* d_out, int out_size, void* d_ws, size_t ws_size,
                              hipStream_t stream) {
  (void)in_sizes; (void)n_in; (void)out_size; (void)ws_size;
  const float* x = (const float*)d_in[0];      // (2,4096,1024) fp32
  const float* gum = (const float*)d_in[1];    // (16,64,64) fp32
  const float* wqkv = (const float*)d_in[2];   // (1024,3072) fp32
  const float* sortw = (const float*)d_in[3];  // (1,8,256,64) fp32
  const float* wout = (const float*)d_in[4];   // (1024,1024) fp32
  const float* bout = (const float*)d_in[5];   // (1024,) fp32
  float* out = (float*)d_out;                  // (2,4096,1024) fp32

  char* ws = (char*)d_ws;
  size_t off = 0;
  auto alloc = [&](size_t bytes) {
    char* p = ws + off;
    off += (bytes + 255) & ~(size_t)255;
    return p;
  };
  ushort* xb = (ushort*)alloc((size_t)8192 * 1024 * 2);
  float* xsum8 = (float*)alloc((size_t)1024 * 1024 * 4);
  ushort* wqkvT = (ushort*)alloc((size_t)3072 * 1024 * 2);
  ushort* woutT = (ushort*)alloc((size_t)1024 * 1024 * 2);
  float* SX = (float*)alloc((size_t)16 * 256 * 64 * 4);
  ushort* Qb = (ushort*)alloc((size_t)16 * 64 * 64 * 128 * 2);
  ushort* Kb = (ushort*)alloc((size_t)16 * 64 * 64 * 128 * 2);
  ushort* VT = (ushort*)alloc((size_t)16 * 64 * 128 * 64 * 2);
  int* idxArr = (int*)alloc((size_t)16 * 64 * 4);
  float* wgtArr = (float*)alloc((size_t)16 * 64 * 4);
  ushort* attn = xb;        // alias: xb dead after qkv gemm
  float* SXP = (float*)Qb;  // alias: 8 MB partials, dead before Qb written

  prep_x<<<1024, 256, 0, stream>>>(x, xb, xsum8);
  transpose_f2b<<<dim3(3072 / 32, 1024 / 32), 256, 0, stream>>>(wqkv, wqkvT, 1024, 3072);
  transpose_f2b<<<dim3(1024 / 32, 1024 / 32), 256, 0, stream>>>(wout, woutT, 1024, 1024);
  sx_gemm_partial<<<dim3(8, 16, 8), 256, 0, stream>>>(xsum8, wqkv, SXP);
  sx_reduce<<<dim3(8, 128), 256, 0, stream>>>(SXP, SX);
  sortnet_sinkhorn<<<16, 256, 0, stream>>>(SX, sortw, gum, idxArr, wgtArr);
  gemm_bt<<<dim3(3072 / 128, 8192 / 128), 256, 0, stream>>>(
      xb, wqkvT, 8192, 3072, 1024, 1, nullptr, nullptr, Qb, Kb, VT);
  attn_kernel<<<16 * 64, 256, 0, stream>>>(Qb, Kb, VT, idxArr, wgtArr, attn);
  gemm_bt<<<dim3(1024 / 128, 8192 / 128), 256, 0, stream>>>(
      attn, woutT, 8192, 1024, 1024, 0, bout, out, nullptr, nullptr, nullptr);
}

// Round 8
// 274.900 us; speedup vs baseline: 1.0411x; 1.0411x over previous
//
#include <hip/hip_runtime.h>
#include <stdint.h>

#define TEMP_ 0.75f
#define EPS_ 1e-6f

typedef __attribute__((ext_vector_type(8))) short bf16x8;
typedef __attribute__((ext_vector_type(4))) float f32x4;

typedef __attribute__((address_space(1))) void gvoid_t;
typedef __attribute__((address_space(3))) void lvoid_t;

__device__ __forceinline__ void async_ld16(const void* g, void* l) {
  __builtin_amdgcn_global_load_lds((gvoid_t*)g, (lvoid_t*)l, 16, 0, 0);
}

__device__ __forceinline__ float b2f(ushort u) {
  return __builtin_bit_cast(float, (uint32_t)u << 16);
}
__device__ __forceinline__ ushort f2b(float f) {
  uint32_t x = __builtin_bit_cast(uint32_t, f);
  x += 0x7fffu + ((x >> 16) & 1u);
  return (ushort)(x >> 16);
}

// ------------------------------------------------------- prep_x: fp32 x -> bf16 xb + fp32 half-bucket sums
__global__ __launch_bounds__(256) void prep_x(
    const float* __restrict__ x, ushort* __restrict__ xb, float* __restrict__ xsum2) {
  const int blk = blockIdx.x;
  const int bu = blk >> 1, half = blk & 1;
  const int b = bu >> 6, u = bu & 63;
  const int c = threadIdx.x * 4;
  const float* src = x + ((size_t)(b * 4096 + u * 64 + half * 32)) * 1024 + c;
  ushort* dst = xb + ((size_t)(b * 4096 + u * 64 + half * 32)) * 1024 + c;
  float s0 = 0.f, s1 = 0.f, s2 = 0.f, s3 = 0.f;
  for (int pos = 0; pos < 32; pos++) {
    float4 v = *(const float4*)(src + (size_t)pos * 1024);
    s0 += v.x; s1 += v.y; s2 += v.z; s3 += v.w;
    ushort4 o;
    o.x = f2b(v.x); o.y = f2b(v.y); o.z = f2b(v.z); o.w = f2b(v.w);
    *(ushort4*)(dst + (size_t)pos * 1024) = o;
  }
  float4 sv = {s0, s1, s2, s3};
  *(float4*)&xsum2[(size_t)blk * 1024 + c] = sv;
}

// ------------------------------------------------------- transpose + fp32->bf16
__global__ __launch_bounds__(256) void transpose_f2b(
    const float* __restrict__ src, ushort* __restrict__ dst, int R, int C) {
  __shared__ float tile[32][33];
  int bx = blockIdx.x * 32;
  int by = blockIdx.y * 32;
  int tx = threadIdx.x & 31, ty = threadIdx.x >> 5;  // 32 x 8
  #pragma unroll
  for (int i = 0; i < 32; i += 8)
    tile[ty + i][tx] = src[(size_t)(by + ty + i) * C + bx + tx];
  __syncthreads();
  #pragma unroll
  for (int i = 0; i < 32; i += 8)
    dst[(size_t)(bx + ty + i) * R + by + tx] = f2b(tile[tx][ty + i]);
}

// ------------------------------------------------------- sx partial: split-K over 8 chunks
// SXP[kc*128 + bu][n]  (n in [0,2048))
__global__ __launch_bounds__(256) void sx_gemm_partial(
    const float* __restrict__ xsum2, const float* __restrict__ wqkv,
    float* __restrict__ SXP) {
  __shared__ float xs[128 * 8];  // k-major: xs[k*8 + r]
  const int cb = blockIdx.x;  // 8 colblocks of 256 n
  const int rt = blockIdx.y;  // 16 rowtiles of 8 bu
  const int kc = blockIdx.z;  // 8 k-chunks of 128
  const int tid = threadIdx.x;
  for (int idx = tid; idx < 1024; idx += 256) {
    int k = idx >> 3, r = idx & 7;
    int bu = rt * 8 + r;
    int kk = kc * 128 + k;
    xs[idx] = xsum2[(size_t)(bu * 2) * 1024 + kk] + xsum2[(size_t)(bu * 2 + 1) * 1024 + kk];
  }
  __syncthreads();
  const int n = cb * 256 + tid;
  float acc[8];
  #pragma unroll
  for (int r = 0; r < 8; r++) acc[r] = 0.f;
  for (int k = 0; k < 128; k++) {
    float w = wqkv[(size_t)(kc * 128 + k) * 3072 + n];
    float4 a0 = *(const float4*)&xs[k * 8];
    float4 a1 = *(const float4*)&xs[k * 8 + 4];
    acc[0] += a0.x * w; acc[1] += a0.y * w; acc[2] += a0.z * w; acc[3] += a0.w * w;
    acc[4] += a1.x * w; acc[5] += a1.y * w; acc[6] += a1.z * w; acc[7] += a1.w * w;
  }
  #pragma unroll
  for (int r = 0; r < 8; r++)
    SXP[(size_t)(kc * 128 + rt * 8 + r) * 2048 + n] = acc[r];
}

// ------------------------------------------------------- sx reduce: fixed-order sum + scatter
// SX layout: [bh][e2(256)][u(64)]
__global__ __launch_bounds__(256) void sx_reduce(
    const float* __restrict__ SXP, float* __restrict__ SX) {
  const int bu = blockIdx.y;
  const int n = blockIdx.x * 256 + threadIdx.x;
  float s = 0.f;
  #pragma unroll
  for (int kc = 0; kc < 8; kc++)
    s += SXP[(size_t)(kc * 128 + bu) * 2048 + n];
  const int head = (n >> 7) & 7;
  const int e2 = ((n >> 10) << 7) | (n & 127);
  const int b = bu >> 6, u = bu & 63;
  SX[((size_t)((b * 8 + head) * 256) + e2) * 64 + u] = s;
}

// ------------------------------------------------------- sortnet + sinkhorn + top1 (fp32, LDS-staged)
__global__ __launch_bounds__(256) void sortnet_sinkhorn(
    const float* __restrict__ SX, const float* __restrict__ sortw,
    const float* __restrict__ gum, int* __restrict__ idxArr,
    float* __restrict__ wgtArr) {
  __shared__ float sxl[64 * 64];  // chunk: [e][u]  16 KB
  __shared__ float wl[64 * 64];   // chunk: [e][c]  16 KB
  __shared__ float rr[64 * 65];   // 16.6 KB
  __shared__ float redA[256];
  __shared__ float redB[256];
  __shared__ int redi[256];
  const int bh = blockIdx.x, tid = threadIdx.x, head = bh & 7;
  const int ui = tid & 15, ci = tid >> 4;  // 4x4 tile position

  float acc[4][4];
  #pragma unroll
  for (int i = 0; i < 4; i++)
    #pragma unroll
    for (int j = 0; j < 4; j++) acc[i][j] = 0.f;

  const f32x4* SX4 = (const f32x4*)(SX + (size_t)bh * 16384);
  const f32x4* W4 = (const f32x4*)(sortw + (size_t)head * 16384);
  f32x4* sxl4 = (f32x4*)sxl;
  f32x4* wl4 = (f32x4*)wl;

  #pragma unroll 1
  for (int ch = 0; ch < 4; ch++) {
    __syncthreads();
    #pragma unroll 1
    for (int g = tid; g < 1024; g += 256) {
      sxl4[g] = SX4[ch * 1024 + g];
      wl4[g] = W4[ch * 1024 + g];
    }
    __syncthreads();
    #pragma unroll 2
    for (int e = 0; e < 64; e++) {
      f32x4 a = sxl4[e * 16 + ui];
      f32x4 w = wl4[e * 16 + ci];
      #pragma unroll
      for (int i = 0; i < 4; i++)
        #pragma unroll
        for (int j = 0; j < 4; j++) acc[i][j] += a[i] * w[j];
    }
  }

  // leaky relu + gumbel + log -> rr
  #pragma unroll
  for (int i = 0; i < 4; i++)
    #pragma unroll
    for (int j = 0; j < 4; j++) {
      int u = ui * 4 + i, c = ci * 4 + j;
      float dot = acc[i][j];
      float r0 = dot > 0.f ? dot : 0.01f * dot;
      float gu = gum[(size_t)bh * 4096 + u * 64 + c];
      float inner = -logf(gu + EPS_) + EPS_;
      float g = -logf(fmaxf(inner, 1e-38f));
      rr[u * 65 + c] = (logf(fmaxf(r0 + EPS_, EPS_)) + g) / TEMP_;
    }
  __syncthreads();

  const int su = tid & 63, sq = tid >> 6;
  #pragma unroll 1
  for (int it = 0; it < 5; it++) {
    {  // row norm (axis c)
      float pm = -1e30f;
      #pragma unroll
      for (int j = 0; j < 16; j++) pm = fmaxf(pm, rr[su * 65 + sq * 16 + j]);
      redA[sq * 64 + su] = pm;
      __syncthreads();
      float m = fmaxf(fmaxf(redA[su], redA[64 + su]), fmaxf(redA[128 + su], redA[192 + su]));
      float ps = 0.f;
      #pragma unroll
      for (int j = 0; j < 16; j++) ps += expf(rr[su * 65 + sq * 16 + j] - m);
      redB[sq * 64 + su] = ps;
      __syncthreads();
      float l = m + logf(redB[su] + redB[64 + su] + redB[128 + su] + redB[192 + su]);
      #pragma unroll
      for (int j = 0; j < 16; j++) rr[su * 65 + sq * 16 + j] -= l;
      __syncthreads();
    }
    {  // col norm (axis u)
      float pm = -1e30f;
      #pragma unroll
      for (int j = 0; j < 16; j++) pm = fmaxf(pm, rr[(sq * 16 + j) * 65 + su]);
      redA[sq * 64 + su] = pm;
      __syncthreads();
      float m = fmaxf(fmaxf(redA[su], redA[64 + su]), fmaxf(redA[128 + su], redA[192 + su]));
      float ps = 0.f;
      #pragma unroll
      for (int j = 0; j < 16; j++) ps += expf(rr[(sq * 16 + j) * 65 + su] - m);
      redB[sq * 64 + su] = ps;
      __syncthreads();
      float l = m + logf(redB[su] + redB[64 + su] + redB[128 + su] + redB[192 + su]);
      #pragma unroll
      for (int j = 0; j < 16; j++) rr[(sq * 16 + j) * 65 + su] -= l;
      __syncthreads();
    }
  }

  {  // first-max argmax over cols (np semantics), 4-way parallel
    float pv = -1e30f;
    int pi = 0;
    #pragma unroll
    for (int j = 0; j < 16; j++) {
      float v = rr[su * 65 + sq * 16 + j];
      if (v > pv) { pv = v; pi = sq * 16 + j; }
    }
    redA[sq * 64 + su] = pv;
    redi[sq * 64 + su] = pi;
    __syncthreads();
    if (tid < 64) {
      float best = -1e30f;
      int bi = 0;
      #pragma unroll
      for (int q = 0; q < 4; q++) {
        float v = redA[q * 64 + tid];
        if (v > best) { best = v; bi = redi[q * 64 + tid]; }
      }
      idxArr[bh * 64 + tid] = bi;
      wgtArr[bh * 64 + tid] = expf(fminf(best, 80.f));
    }
  }
}

// ------------------------------------------------------- GEMM, bf16 MFMA, BK=64
// C = A(MxK) @ BT(NxK)^T. Halved barrier count vs BK=32 (16 iters at K=1024).
// LDS 32 KB. Staging: 8 global_load_lds_dwordx4 per wave per iter.
__global__ __launch_bounds__(256, 2) void gemm_bt(
    const ushort* __restrict__ A, const ushort* __restrict__ BT,
    int M, int N, int K, int mode,
    const float* __restrict__ bias, float* __restrict__ Cout,
    ushort* __restrict__ Qb, ushort* __restrict__ Kb, ushort* __restrict__ VT) {
  __shared__ ushort As[128 * 64];
  __shared__ ushort Bs[128 * 64];
  const int tid = threadIdx.x;
  const int wave = tid >> 6, lane = tid & 63;
  const int quad = lane >> 4, l16 = lane & 15;
  const int m0 = blockIdx.y * 128, n0 = blockIdx.x * 128;
  const int wm = (wave >> 1) * 64, wn = (wave & 1) * 64;

  f32x4 acc[4][4];
  #pragma unroll
  for (int i = 0; i < 4; i++)
    #pragma unroll
    for (int j = 0; j < 4; j++) acc[i][j] = (f32x4){0.f, 0.f, 0.f, 0.f};

  const int srow = wave * 32 + (lane >> 3);  // +t*8, t in 0..3
  const int schunk = (lane & 7) * 8;

  for (int k0 = 0; k0 < K; k0 += 64) {
    __syncthreads();
    {
      const ushort* gA0 = A + (uint64_t)(m0 + srow) * K + k0 + schunk;
      const ushort* gB0 = BT + (uint64_t)(n0 + srow) * K + k0 + schunk;
      ushort* lA = (ushort*)As + (wave * 32) * 64;
      ushort* lB = (ushort*)Bs + (wave * 32) * 64;
      #pragma unroll
      for (int t = 0; t < 4; t++) {
        async_ld16(gA0 + (uint64_t)(t * 8) * K, lA + t * 8 * 64);
        async_ld16(gB0 + (uint64_t)(t * 8) * K, lB + t * 8 * 64);
      }
    }
    __syncthreads();
    #pragma unroll
    for (int kk = 0; kk < 2; kk++) {
      bf16x8 af[4], bfr[4];
      #pragma unroll
      for (int mt = 0; mt < 4; mt++)
        af[mt] = *(const bf16x8*)&As[(wm + mt * 16 + l16) * 64 + kk * 32 + quad * 8];
      #pragma unroll
      for (int nt = 0; nt < 4; nt++)
        bfr[nt] = *(const bf16x8*)&Bs[(wn + nt * 16 + l16) * 64 + kk * 32 + quad * 8];
      #pragma unroll
      for (int mt = 0; mt < 4; mt++)
        #pragma unroll
        for (int nt = 0; nt < 4; nt++)
          acc[mt][nt] = __builtin_amdgcn_mfma_f32_16x16x32_bf16(af[mt], bfr[nt], acc[mt][nt], 0, 0, 0);
    }
  }

  if (mode == 0) {
    #pragma unroll
    for (int mt = 0; mt < 4; mt++) {
      int row = m0 + wm + mt * 16 + quad * 4;
      #pragma unroll
      for (int nt = 0; nt < 4; nt++) {
        int col = n0 + wn + nt * 16 + l16;
        float bv = bias[col];
        #pragma unroll
        for (int r = 0; r < 4; r++)
          Cout[(uint64_t)(row + r) * N + col] = acc[mt][nt][r] + bv;
      }
    }
  } else {
    int which = blockIdx.x >> 3;  // 0=q,1=k,2=v  (n0 multiple of 128)
    int head = blockIdx.x & 7;
    #pragma unroll
    for (int mt = 0; mt < 4; mt++) {
      int mrow = m0 + wm + mt * 16 + quad * 4;
      int bidx = mrow >> 12;
      int ttok = mrow & 4095;
      int u = ttok >> 6, pos = ttok & 63;
      int bh = bidx * 8 + head;
      #pragma unroll
      for (int nt = 0; nt < 4; nt++) {
        int e = wn + nt * 16 + l16;
        if (which == 2) {
          ushort4 pk;
          pk.x = f2b(acc[mt][nt][0]);
          pk.y = f2b(acc[mt][nt][1]);
          pk.z = f2b(acc[mt][nt][2]);
          pk.w = f2b(acc[mt][nt][3]);
          *(ushort4*)&VT[((uint64_t)(bh * 64 + u) * 128 + e) * 64 + pos] = pk;
        } else {
          ushort* dst = (which == 0) ? Qb : Kb;
          #pragma unroll
          for (int r = 0; r < 4; r++)
            dst[((uint64_t)(bh * 64 + u) * 64 + pos + r) * 128 + e] = f2b(acc[mt][nt][r]);
        }
      }
    }
  }
}

// ------------------------------------------------------- bucketed attention
#define KSTR 136
__global__ __launch_bounds__(256) void attn_kernel(
    const ushort* __restrict__ Qb, const ushort* __restrict__ Kb,
    const ushort* __restrict__ VT, const int* __restrict__ idxArr,
    const float* __restrict__ wgtArr, ushort* __restrict__ attn_out) {
  __shared__ ushort Qs[64 * KSTR];   // Q, later P
  __shared__ ushort Ks[128 * KSTR];  // K2[j][e], later V2^T[e][j]
  const int blk = blockIdx.x;
  const int u = blk & 63, bh = blk >> 6;
  const int tid = threadIdx.x, wave = tid >> 6, lane = tid & 63;
  const int quad = lane >> 4, l16 = lane & 15;
  const int vu = idxArr[bh * 64 + u] & 63;
  const float w = wgtArr[bh * 64 + u];

  const ushort* Qsrc = Qb + (uint64_t)(bh * 64 + u) * 8192;
  const ushort* Ksrc0 = Kb + (uint64_t)(bh * 64 + vu) * 8192;
  const ushort* Ksrc1 = Kb + (uint64_t)(bh * 64 + u) * 8192;
  const ushort* Vsrc0 = VT + (uint64_t)(bh * 64 + vu) * 8192;
  const ushort* Vsrc1 = VT + (uint64_t)(bh * 64 + u) * 8192;

  for (int g = tid; g < 64 * 16; g += 256) {
    int eb = g & 15, p = g >> 4;
    *(bf16x8*)&Qs[p * KSTR + eb * 8] = *(const bf16x8*)&Qsrc[p * 128 + eb * 8];
  }
  for (int g = tid; g < 128 * 16; g += 256) {
    int eb = g & 15, j = g >> 4;
    const ushort* s = (j < 64) ? &Ksrc0[j * 128 + eb * 8] : &Ksrc1[(j - 64) * 128 + eb * 8];
    *(bf16x8*)&Ks[j * KSTR + eb * 8] = *(const bf16x8*)s;
  }
  __syncthreads();

  f32x4 S[8];
  #pragma unroll
  for (int nt = 0; nt < 8; nt++) S[nt] = (f32x4){0.f, 0.f, 0.f, 0.f};
  #pragma unroll
  for (int kk = 0; kk < 4; kk++) {
    bf16x8 aq = *(const bf16x8*)&Qs[(wave * 16 + l16) * KSTR + kk * 32 + quad * 8];
    #pragma unroll
    for (int nt = 0; nt < 8; nt++) {
      bf16x8 bk = *(const bf16x8*)&Ks[(nt * 16 + l16) * KSTR + kk * 32 + quad * 8];
      S[nt] = __builtin_amdgcn_mfma_f32_16x16x32_bf16(aq, bk, S[nt], 0, 0, 0);
    }
  }
  __syncthreads();  // all waves done reading K2

  // stage V2^T into Ks
  for (int g = tid; g < 128 * 16; g += 256) {
    int jb = g & 15, e = g >> 4;
    const ushort* s = (jb < 8) ? &Vsrc0[e * 64 + jb * 8] : &Vsrc1[e * 64 + (jb - 8) * 8];
    *(bf16x8*)&Ks[e * KSTR + jb * 8] = *(const bf16x8*)s;
  }

  const float scale = 0.03125f;  // (d=1024)^-0.5
  float rowmax[4] = {-1e30f, -1e30f, -1e30f, -1e30f};
  #pragma unroll
  for (int nt = 0; nt < 8; nt++) {
    float cs = scale * ((nt < 4) ? w : 1.0f);
    #pragma unroll
    for (int r = 0; r < 4; r++) {
      S[nt][r] *= cs;
      rowmax[r] = fmaxf(rowmax[r], S[nt][r]);
    }
  }
  #pragma unroll
  for (int off = 1; off < 16; off <<= 1)
    #pragma unroll
    for (int r = 0; r < 4; r++)
      rowmax[r] = fmaxf(rowmax[r], __shfl_xor(rowmax[r], off, 64));
  float rowsum[4] = {0.f, 0.f, 0.f, 0.f};
  #pragma unroll
  for (int nt = 0; nt < 8; nt++)
    #pragma unroll
    for (int r = 0; r < 4; r++) {
      float p = expf(S[nt][r] - rowmax[r]);
      S[nt][r] = p;
      rowsum[r] += p;
    }
  #pragma unroll
  for (int off = 1; off < 16; off <<= 1)
    #pragma unroll
    for (int r = 0; r < 4; r++)
      rowsum[r] += __shfl_xor(rowsum[r], off, 64);
  float rinv[4];
  #pragma unroll
  for (int r = 0; r < 4; r++) rinv[r] = 1.0f / rowsum[r];

  #pragma unroll
  for (int nt = 0; nt < 8; nt++)
    #pragma unroll
    for (int r = 0; r < 4; r++) {
      float pv = S[nt][r] * rinv[r] * ((nt < 4) ? w : 1.0f);
      Qs[(wave * 16 + quad * 4 + r) * KSTR + nt * 16 + l16] = f2b(pv);
    }
  __syncthreads();  // V2^T staged

  f32x4 O[8];
  #pragma unroll
  for (int nt = 0; nt < 8; nt++) O[nt] = (f32x4){0.f, 0.f, 0.f, 0.f};
  #pragma unroll
  for (int kk = 0; kk < 4; kk++) {
    bf16x8 ap = *(const bf16x8*)&Qs[(wave * 16 + l16) * KSTR + kk * 32 + quad * 8];
    #pragma unroll
    for (int nt = 0; nt < 8; nt++) {
      bf16x8 bv = *(const bf16x8*)&Ks[(nt * 16 + l16) * KSTR + kk * 32 + quad * 8];
      O[nt] = __builtin_amdgcn_mfma_f32_16x16x32_bf16(ap, bv, O[nt], 0, 0, 0);
    }
  }

  const int bidx = bh >> 3, head = bh & 7;
  uint64_t rowbase =
      (uint64_t)(bidx * 4096 + u * 64 + wave * 16 + quad * 4) * 1024 + head * 128;
  #pragma unroll
  for (int nt = 0; nt < 8; nt++)
    #pragma unroll
    for (int r = 0; r < 4; r++)
      attn_out[rowbase + (uint64_t)r * 1024 + nt * 16 + l16] = f2b(O[nt][r]);
}

// ---------------------------------------------------------------- launch
extern "C" void kernel_launch(void* const* d_in, const int* in_sizes, int n_in,
                              void* d_out, int out_size, void* d_ws, size_t ws_size,
                              hipStream_t stream) {
  (void)in_sizes; (void)n_in; (void)out_size; (void)ws_size;
  const float* x = (const float*)d_in[0];      // (2,4096,1024) fp32
  const float* gum = (const float*)d_in[1];    // (16,64,64) fp32
  const float* wqkv = (const float*)d_in[2];   // (1024,3072) fp32
  const float* sortw = (const float*)d_in[3];  // (1,8,256,64) fp32
  const float* wout = (const float*)d_in[4];   // (1024,1024) fp32
  const float* bout = (const float*)d_in[5];   // (1024,) fp32
  float* out = (float*)d_out;                  // (2,4096,1024) fp32

  char* ws = (char*)d_ws;
  size_t off = 0;
  auto alloc = [&](size_t bytes) {
    char* p = ws + off;
    off += (bytes + 255) & ~(size_t)255;
    return p;
  };
  ushort* xb = (ushort*)alloc((size_t)8192 * 1024 * 2);
  float* xsum2 = (float*)alloc((size_t)256 * 1024 * 4);
  ushort* wqkvT = (ushort*)alloc((size_t)3072 * 1024 * 2);
  ushort* woutT = (ushort*)alloc((size_t)1024 * 1024 * 2);
  float* SX = (float*)alloc((size_t)16 * 256 * 64 * 4);
  ushort* Qb = (ushort*)alloc((size_t)16 * 64 * 64 * 128 * 2);
  ushort* Kb = (ushort*)alloc((size_t)16 * 64 * 64 * 128 * 2);
  ushort* VT = (ushort*)alloc((size_t)16 * 64 * 128 * 64 * 2);
  int* idxArr = (int*)alloc((size_t)16 * 64 * 4);
  float* wgtArr = (float*)alloc((size_t)16 * 64 * 4);
  ushort* attn = xb;        // alias: xb dead after qkv gemm
  float* SXP = (float*)Qb;  // alias: 8 MB partials, dead before Qb written

  prep_x<<<256, 256, 0, stream>>>(x, xb, xsum2);
  transpose_f2b<<<dim3(3072 / 32, 1024 / 32), 256, 0, stream>>>(wqkv, wqkvT, 1024, 3072);
  transpose_f2b<<<dim3(1024 / 32, 1024 / 32), 256, 0, stream>>>(wout, woutT, 1024, 1024);
  sx_gemm_partial<<<dim3(8, 16, 8), 256, 0, stream>>>(xsum2, wqkv, SXP);
  sx_reduce<<<dim3(8, 128), 256, 0, stream>>>(SXP, SX);
  sortnet_sinkhorn<<<16, 256, 0, stream>>>(SX, sortw, gum, idxArr, wgtArr);
  gemm_bt<<<dim3(3072 / 128, 8192 / 128), 256, 0, stream>>>(
      xb, wqkvT, 8192, 3072, 1024, 1, nullptr, nullptr, Qb, Kb, VT);
  attn_kernel<<<16 * 64, 256, 0, stream>>>(Qb, Kb, VT, idxArr, wgtArr, attn);
  gemm_bt<<<dim3(1024 / 128, 8192 / 128), 256, 0, stream>>>(
      attn, woutT, 8192, 1024, 1024, 0, bout, out, nullptr, nullptr, nullptr);
}

// Round 9
// 261.459 us; speedup vs baseline: 1.0946x; 1.0514x over previous
//
#include <hip/hip_runtime.h>
#include <stdint.h>

#define TEMP_ 0.75f
#define EPS_ 1e-6f

typedef __attribute__((ext_vector_type(8))) short bf16x8;
typedef __attribute__((ext_vector_type(4))) float f32x4;

typedef __attribute__((address_space(1))) void gvoid_t;
typedef __attribute__((address_space(3))) void lvoid_t;

__device__ __forceinline__ void async_ld16(const void* g, void* l) {
  __builtin_amdgcn_global_load_lds((gvoid_t*)g, (lvoid_t*)l, 16, 0, 0);
}

__device__ __forceinline__ float b2f(ushort u) {
  return __builtin_bit_cast(float, (uint32_t)u << 16);
}
__device__ __forceinline__ ushort f2b(float f) {
  uint32_t x = __builtin_bit_cast(uint32_t, f);
  x += 0x7fffu + ((x >> 16) & 1u);
  return (ushort)(x >> 16);
}

// ------------------------------------------------------- prep_x: fp32 x -> bf16 xb + fp32 half-bucket sums
__global__ __launch_bounds__(256) void prep_x(
    const float* __restrict__ x, ushort* __restrict__ xb, float* __restrict__ xsum2) {
  const int blk = blockIdx.x;
  const int bu = blk >> 1, half = blk & 1;
  const int b = bu >> 6, u = bu & 63;
  const int c = threadIdx.x * 4;
  const float* src = x + ((size_t)(b * 4096 + u * 64 + half * 32)) * 1024 + c;
  ushort* dst = xb + ((size_t)(b * 4096 + u * 64 + half * 32)) * 1024 + c;
  float s0 = 0.f, s1 = 0.f, s2 = 0.f, s3 = 0.f;
  for (int pos = 0; pos < 32; pos++) {
    float4 v = *(const float4*)(src + (size_t)pos * 1024);
    s0 += v.x; s1 += v.y; s2 += v.z; s3 += v.w;
    ushort4 o;
    o.x = f2b(v.x); o.y = f2b(v.y); o.z = f2b(v.z); o.w = f2b(v.w);
    *(ushort4*)(dst + (size_t)pos * 1024) = o;
  }
  float4 sv = {s0, s1, s2, s3};
  *(float4*)&xsum2[(size_t)blk * 1024 + c] = sv;
}

// ------------------------------------------------------- transpose + fp32->bf16
__global__ __launch_bounds__(256) void transpose_f2b(
    const float* __restrict__ src, ushort* __restrict__ dst, int R, int C) {
  __shared__ float tile[32][33];
  int bx = blockIdx.x * 32;
  int by = blockIdx.y * 32;
  int tx = threadIdx.x & 31, ty = threadIdx.x >> 5;  // 32 x 8
  #pragma unroll
  for (int i = 0; i < 32; i += 8)
    tile[ty + i][tx] = src[(size_t)(by + ty + i) * C + bx + tx];
  __syncthreads();
  #pragma unroll
  for (int i = 0; i < 32; i += 8)
    dst[(size_t)(bx + ty + i) * R + by + tx] = f2b(tile[tx][ty + i]);
}

// ------------------------------------------------------- sx partial: split-K over 8 chunks
// SXP[kc*128 + bu][n]  (n in [0,2048))
__global__ __launch_bounds__(256) void sx_gemm_partial(
    const float* __restrict__ xsum2, const float* __restrict__ wqkv,
    float* __restrict__ SXP) {
  __shared__ float xs[128 * 8];  // k-major: xs[k*8 + r]
  const int cb = blockIdx.x;  // 8 colblocks of 256 n
  const int rt = blockIdx.y;  // 16 rowtiles of 8 bu
  const int kc = blockIdx.z;  // 8 k-chunks of 128
  const int tid = threadIdx.x;
  for (int idx = tid; idx < 1024; idx += 256) {
    int k = idx >> 3, r = idx & 7;
    int bu = rt * 8 + r;
    int kk = kc * 128 + k;
    xs[idx] = xsum2[(size_t)(bu * 2) * 1024 + kk] + xsum2[(size_t)(bu * 2 + 1) * 1024 + kk];
  }
  __syncthreads();
  const int n = cb * 256 + tid;
  float acc[8];
  #pragma unroll
  for (int r = 0; r < 8; r++) acc[r] = 0.f;
  for (int k = 0; k < 128; k++) {
    float w = wqkv[(size_t)(kc * 128 + k) * 3072 + n];
    float4 a0 = *(const float4*)&xs[k * 8];
    float4 a1 = *(const float4*)&xs[k * 8 + 4];
    acc[0] += a0.x * w; acc[1] += a0.y * w; acc[2] += a0.z * w; acc[3] += a0.w * w;
    acc[4] += a1.x * w; acc[5] += a1.y * w; acc[6] += a1.z * w; acc[7] += a1.w * w;
  }
  #pragma unroll
  for (int r = 0; r < 8; r++)
    SXP[(size_t)(kc * 128 + rt * 8 + r) * 2048 + n] = acc[r];
}

// ------------------------------------------------------- sx reduce: fixed-order sum + scatter
// SX layout: [bh][e2(256)][u(64)]
__global__ __launch_bounds__(256) void sx_reduce(
    const float* __restrict__ SXP, float* __restrict__ SX) {
  const int bu = blockIdx.y;
  const int n = blockIdx.x * 256 + threadIdx.x;
  float s = 0.f;
  #pragma unroll
  for (int kc = 0; kc < 8; kc++)
    s += SXP[(size_t)(kc * 128 + bu) * 2048 + n];
  const int head = (n >> 7) & 7;
  const int e2 = ((n >> 10) << 7) | (n & 127);
  const int b = bu >> 6, u = bu & 63;
  SX[((size_t)((b * 8 + head) * 256) + e2) * 64 + u] = s;
}

// ------------------------------------------------------- sortnet + sinkhorn + top1 (fp32, LDS-staged)
__global__ __launch_bounds__(256) void sortnet_sinkhorn(
    const float* __restrict__ SX, const float* __restrict__ sortw,
    const float* __restrict__ gum, int* __restrict__ idxArr,
    float* __restrict__ wgtArr) {
  __shared__ float sxl[64 * 64];  // chunk: [e][u]  16 KB
  __shared__ float wl[64 * 64];   // chunk: [e][c]  16 KB
  __shared__ float rr[64 * 65];   // 16.6 KB
  __shared__ float redA[256];
  __shared__ float redB[256];
  __shared__ int redi[256];
  const int bh = blockIdx.x, tid = threadIdx.x, head = bh & 7;
  const int ui = tid & 15, ci = tid >> 4;  // 4x4 tile position

  float acc[4][4];
  #pragma unroll
  for (int i = 0; i < 4; i++)
    #pragma unroll
    for (int j = 0; j < 4; j++) acc[i][j] = 0.f;

  const f32x4* SX4 = (const f32x4*)(SX + (size_t)bh * 16384);
  const f32x4* W4 = (const f32x4*)(sortw + (size_t)head * 16384);
  f32x4* sxl4 = (f32x4*)sxl;
  f32x4* wl4 = (f32x4*)wl;

  #pragma unroll 1
  for (int ch = 0; ch < 4; ch++) {
    __syncthreads();
    #pragma unroll 1
    for (int g = tid; g < 1024; g += 256) {
      sxl4[g] = SX4[ch * 1024 + g];
      wl4[g] = W4[ch * 1024 + g];
    }
    __syncthreads();
    #pragma unroll 2
    for (int e = 0; e < 64; e++) {
      f32x4 a = sxl4[e * 16 + ui];
      f32x4 w = wl4[e * 16 + ci];
      #pragma unroll
      for (int i = 0; i < 4; i++)
        #pragma unroll
        for (int j = 0; j < 4; j++) acc[i][j] += a[i] * w[j];
    }
  }

  // leaky relu + gumbel + log -> rr
  #pragma unroll
  for (int i = 0; i < 4; i++)
    #pragma unroll
    for (int j = 0; j < 4; j++) {
      int u = ui * 4 + i, c = ci * 4 + j;
      float dot = acc[i][j];
      float r0 = dot > 0.f ? dot : 0.01f * dot;
      float gu = gum[(size_t)bh * 4096 + u * 64 + c];
      float inner = -logf(gu + EPS_) + EPS_;
      float g = -logf(fmaxf(inner, 1e-38f));
      rr[u * 65 + c] = (logf(fmaxf(r0 + EPS_, EPS_)) + g) / TEMP_;
    }
  __syncthreads();

  const int su = tid & 63, sq = tid >> 6;
  #pragma unroll 1
  for (int it = 0; it < 5; it++) {
    {  // row norm (axis c)
      float pm = -1e30f;
      #pragma unroll
      for (int j = 0; j < 16; j++) pm = fmaxf(pm, rr[su * 65 + sq * 16 + j]);
      redA[sq * 64 + su] = pm;
      __syncthreads();
      float m = fmaxf(fmaxf(redA[su], redA[64 + su]), fmaxf(redA[128 + su], redA[192 + su]));
      float ps = 0.f;
      #pragma unroll
      for (int j = 0; j < 16; j++) ps += expf(rr[su * 65 + sq * 16 + j] - m);
      redB[sq * 64 + su] = ps;
      __syncthreads();
      float l = m + logf(redB[su] + redB[64 + su] + redB[128 + su] + redB[192 + su]);
      #pragma unroll
      for (int j = 0; j < 16; j++) rr[su * 65 + sq * 16 + j] -= l;
      __syncthreads();
    }
    {  // col norm (axis u)
      float pm = -1e30f;
      #pragma unroll
      for (int j = 0; j < 16; j++) pm = fmaxf(pm, rr[(sq * 16 + j) * 65 + su]);
      redA[sq * 64 + su] = pm;
      __syncthreads();
      float m = fmaxf(fmaxf(redA[su], redA[64 + su]), fmaxf(redA[128 + su], redA[192 + su]));
      float ps = 0.f;
      #pragma unroll
      for (int j = 0; j < 16; j++) ps += expf(rr[(sq * 16 + j) * 65 + su] - m);
      redB[sq * 64 + su] = ps;
      __syncthreads();
      float l = m + logf(redB[su] + redB[64 + su] + redB[128 + su] + redB[192 + su]);
      #pragma unroll
      for (int j = 0; j < 16; j++) rr[(sq * 16 + j) * 65 + su] -= l;
      __syncthreads();
    }
  }

  {  // first-max argmax over cols (np semantics), 4-way parallel
    float pv = -1e30f;
    int pi = 0;
    #pragma unroll
    for (int j = 0; j < 16; j++) {
      float v = rr[su * 65 + sq * 16 + j];
      if (v > pv) { pv = v; pi = sq * 16 + j; }
    }
    redA[sq * 64 + su] = pv;
    redi[sq * 64 + su] = pi;
    __syncthreads();
    if (tid < 64) {
      float best = -1e30f;
      int bi = 0;
      #pragma unroll
      for (int q = 0; q < 4; q++) {
        float v = redA[q * 64 + tid];
        if (v > best) { best = v; bi = redi[q * 64 + tid]; }
      }
      idxArr[bh * 64 + tid] = bi;
      wgtArr[bh * 64 + tid] = expf(fminf(best, 80.f));
    }
  }
}

// ------------------------------------------------------- GEMM, bf16 MFMA, BK=64 dual-buffer
// C = A(MxK) @ BT(NxK)^T. 16 barriers at K=1024 (BK=64) but round-6 64B-stride
// LDS geometry (conflict-free measured config): lo/hi half-buffers of 128x32.
__global__ __launch_bounds__(256, 2) void gemm_bt(
    const ushort* __restrict__ A, const ushort* __restrict__ BT,
    int M, int N, int K, int mode,
    const float* __restrict__ bias, float* __restrict__ Cout,
    ushort* __restrict__ Qb, ushort* __restrict__ Kb, ushort* __restrict__ VT) {
  __shared__ ushort As_lo[128 * 32];
  __shared__ ushort As_hi[128 * 32];
  __shared__ ushort Bs_lo[128 * 32];
  __shared__ ushort Bs_hi[128 * 32];
  const int tid = threadIdx.x;
  const int wave = tid >> 6, lane = tid & 63;
  const int quad = lane >> 4, l16 = lane & 15;
  const int m0 = blockIdx.y * 128, n0 = blockIdx.x * 128;
  const int wm = (wave >> 1) * 64, wn = (wave & 1) * 64;

  f32x4 acc[4][4];
  #pragma unroll
  for (int i = 0; i < 4; i++)
    #pragma unroll
    for (int j = 0; j < 4; j++) acc[i][j] = (f32x4){0.f, 0.f, 0.f, 0.f};

  const int srow = wave * 32 + (lane >> 2);
  const int schunk = (lane & 3) * 8;

  for (int k0 = 0; k0 < K; k0 += 64) {
    __syncthreads();
    {
      const ushort* gA0 = A + (uint64_t)(m0 + srow) * K + k0 + schunk;
      const ushort* gB0 = BT + (uint64_t)(n0 + srow) * K + k0 + schunk;
      const int lofs = (wave * 32) * 32;  // wave-uniform base
      async_ld16(gA0, (ushort*)As_lo + lofs);
      async_ld16(gA0 + (uint64_t)16 * K, (ushort*)As_lo + lofs + 16 * 32);
      async_ld16(gA0 + 32, (ushort*)As_hi + lofs);
      async_ld16(gA0 + (uint64_t)16 * K + 32, (ushort*)As_hi + lofs + 16 * 32);
      async_ld16(gB0, (ushort*)Bs_lo + lofs);
      async_ld16(gB0 + (uint64_t)16 * K, (ushort*)Bs_lo + lofs + 16 * 32);
      async_ld16(gB0 + 32, (ushort*)Bs_hi + lofs);
      async_ld16(gB0 + (uint64_t)16 * K + 32, (ushort*)Bs_hi + lofs + 16 * 32);
    }
    __syncthreads();
    #pragma unroll
    for (int kk = 0; kk < 2; kk++) {
      const ushort* Ab = kk ? As_hi : As_lo;
      const ushort* Bb = kk ? Bs_hi : Bs_lo;
      bf16x8 af[4], bfr[4];
      #pragma unroll
      for (int mt = 0; mt < 4; mt++)
        af[mt] = *(const bf16x8*)&Ab[(wm + mt * 16 + l16) * 32 + quad * 8];
      #pragma unroll
      for (int nt = 0; nt < 4; nt++)
        bfr[nt] = *(const bf16x8*)&Bb[(wn + nt * 16 + l16) * 32 + quad * 8];
      #pragma unroll
      for (int mt = 0; mt < 4; mt++)
        #pragma unroll
        for (int nt = 0; nt < 4; nt++)
          acc[mt][nt] = __builtin_amdgcn_mfma_f32_16x16x32_bf16(af[mt], bfr[nt], acc[mt][nt], 0, 0, 0);
    }
  }

  if (mode == 0) {
    #pragma unroll
    for (int mt = 0; mt < 4; mt++) {
      int row = m0 + wm + mt * 16 + quad * 4;
      #pragma unroll
      for (int nt = 0; nt < 4; nt++) {
        int col = n0 + wn + nt * 16 + l16;
        float bv = bias[col];
        #pragma unroll
        for (int r = 0; r < 4; r++)
          Cout[(uint64_t)(row + r) * N + col] = acc[mt][nt][r] + bv;
      }
    }
  } else {
    int which = blockIdx.x >> 3;  // 0=q,1=k,2=v  (n0 multiple of 128)
    int head = blockIdx.x & 7;
    #pragma unroll
    for (int mt = 0; mt < 4; mt++) {
      int mrow = m0 + wm + mt * 16 + quad * 4;
      int bidx = mrow >> 12;
      int ttok = mrow & 4095;
      int u = ttok >> 6, pos = ttok & 63;
      int bh = bidx * 8 + head;
      #pragma unroll
      for (int nt = 0; nt < 4; nt++) {
        int e = wn + nt * 16 + l16;
        if (which == 2) {
          ushort4 pk;
          pk.x = f2b(acc[mt][nt][0]);
          pk.y = f2b(acc[mt][nt][1]);
          pk.z = f2b(acc[mt][nt][2]);
          pk.w = f2b(acc[mt][nt][3]);
          *(ushort4*)&VT[((uint64_t)(bh * 64 + u) * 128 + e) * 64 + pos] = pk;
        } else {
          ushort* dst = (which == 0) ? Qb : Kb;
          #pragma unroll
          for (int r = 0; r < 4; r++)
            dst[((uint64_t)(bh * 64 + u) * 64 + pos + r) * 128 + e] = f2b(acc[mt][nt][r]);
        }
      }
    }
  }
}

// ------------------------------------------------------- bucketed attention
#define KSTR 136
__global__ __launch_bounds__(256) void attn_kernel(
    const ushort* __restrict__ Qb, const ushort* __restrict__ Kb,
    const ushort* __restrict__ VT, const int* __restrict__ idxArr,
    const float* __restrict__ wgtArr, ushort* __restrict__ attn_out) {
  __shared__ ushort Qs[64 * KSTR];   // Q, later P
  __shared__ ushort Ks[128 * KSTR];  // K2[j][e], later V2^T[e][j]
  const int blk = blockIdx.x;
  const int u = blk & 63, bh = blk >> 6;
  const int tid = threadIdx.x, wave = tid >> 6, lane = tid & 63;
  const int quad = lane >> 4, l16 = lane & 15;
  const int vu = idxArr[bh * 64 + u] & 63;
  const float w = wgtArr[bh * 64 + u];

  const ushort* Qsrc = Qb + (uint64_t)(bh * 64 + u) * 8192;
  const ushort* Ksrc0 = Kb + (uint64_t)(bh * 64 + vu) * 8192;
  const ushort* Ksrc1 = Kb + (uint64_t)(bh * 64 + u) * 8192;
  const ushort* Vsrc0 = VT + (uint64_t)(bh * 64 + vu) * 8192;
  const ushort* Vsrc1 = VT + (uint64_t)(bh * 64 + u) * 8192;

  for (int g = tid; g < 64 * 16; g += 256) {
    int eb = g & 15, p = g >> 4;
    *(bf16x8*)&Qs[p * KSTR + eb * 8] = *(const bf16x8*)&Qsrc[p * 128 + eb * 8];
  }
  for (int g = tid; g < 128 * 16; g += 256) {
    int eb = g & 15, j = g >> 4;
    const ushort* s = (j < 64) ? &Ksrc0[j * 128 + eb * 8] : &Ksrc1[(j - 64) * 128 + eb * 8];
    *(bf16x8*)&Ks[j * KSTR + eb * 8] = *(const bf16x8*)s;
  }
  __syncthreads();

  f32x4 S[8];
  #pragma unroll
  for (int nt = 0; nt < 8; nt++) S[nt] = (f32x4){0.f, 0.f, 0.f, 0.f};
  #pragma unroll
  for (int kk = 0; kk < 4; kk++) {
    bf16x8 aq = *(const bf16x8*)&Qs[(wave * 16 + l16) * KSTR + kk * 32 + quad * 8];
    #pragma unroll
    for (int nt = 0; nt < 8; nt++) {
      bf16x8 bk = *(const bf16x8*)&Ks[(nt * 16 + l16) * KSTR + kk * 32 + quad * 8];
      S[nt] = __builtin_amdgcn_mfma_f32_16x16x32_bf16(aq, bk, S[nt], 0, 0, 0);
    }
  }
  __syncthreads();  // all waves done reading K2

  // stage V2^T into Ks
  for (int g = tid; g < 128 * 16; g += 256) {
    int jb = g & 15, e = g >> 4;
    const ushort* s = (jb < 8) ? &Vsrc0[e * 64 + jb * 8] : &Vsrc1[e * 64 + (jb - 8) * 8];
    *(bf16x8*)&Ks[e * KSTR + jb * 8] = *(const bf16x8*)s;
  }

  const float scale = 0.03125f;  // (d=1024)^-0.5
  float rowmax[4] = {-1e30f, -1e30f, -1e30f, -1e30f};
  #pragma unroll
  for (int nt = 0; nt < 8; nt++) {
    float cs = scale * ((nt < 4) ? w : 1.0f);
    #pragma unroll
    for (int r = 0; r < 4; r++) {
      S[nt][r] *= cs;
      rowmax[r] = fmaxf(rowmax[r], S[nt][r]);
    }
  }
  #pragma unroll
  for (int off = 1; off < 16; off <<= 1)
    #pragma unroll
    for (int r = 0; r < 4; r++)
      rowmax[r] = fmaxf(rowmax[r], __shfl_xor(rowmax[r], off, 64));
  float rowsum[4] = {0.f, 0.f, 0.f, 0.f};
  #pragma unroll
  for (int nt = 0; nt < 8; nt++)
    #pragma unroll
    for (int r = 0; r < 4; r++) {
      float p = expf(S[nt][r] - rowmax[r]);
      S[nt][r] = p;
      rowsum[r] += p;
    }
  #pragma unroll
  for (int off = 1; off < 16; off <<= 1)
    #pragma unroll
    for (int r = 0; r < 4; r++)
      rowsum[r] += __shfl_xor(rowsum[r], off, 64);
  float rinv[4];
  #pragma unroll
  for (int r = 0; r < 4; r++) rinv[r] = 1.0f / rowsum[r];

  #pragma unroll
  for (int nt = 0; nt < 8; nt++)
    #pragma unroll
    for (int r = 0; r < 4; r++) {
      float pv = S[nt][r] * rinv[r] * ((nt < 4) ? w : 1.0f);
      Qs[(wave * 16 + quad * 4 + r) * KSTR + nt * 16 + l16] = f2b(pv);
    }
  __syncthreads();  // V2^T staged

  f32x4 O[8];
  #pragma unroll
  for (int nt = 0; nt < 8; nt++) O[nt] = (f32x4){0.f, 0.f, 0.f, 0.f};
  #pragma unroll
  for (int kk = 0; kk < 4; kk++) {
    bf16x8 ap = *(const bf16x8*)&Qs[(wave * 16 + l16) * KSTR + kk * 32 + quad * 8];
    #pragma unroll
    for (int nt = 0; nt < 8; nt++) {
      bf16x8 bv = *(const bf16x8*)&Ks[(nt * 16 + l16) * KSTR + kk * 32 + quad * 8];
      O[nt] = __builtin_amdgcn_mfma_f32_16x16x32_bf16(ap, bv, O[nt], 0, 0, 0);
    }
  }

  const int bidx = bh >> 3, head = bh & 7;
  uint64_t rowbase =
      (uint64_t)(bidx * 4096 + u * 64 + wave * 16 + quad * 4) * 1024 + head * 128;
  #pragma unroll
  for (int nt = 0; nt < 8; nt++)
    #pragma unroll
    for (int r = 0; r < 4; r++)
      attn_out[rowbase + (uint64_t)r * 1024 + nt * 16 + l16] = f2b(O[nt][r]);
}

// ---------------------------------------------------------------- launch
extern "C" void kernel_launch(void* const* d_in, const int* in_sizes, int n_in,
                              void* d_out, int out_size, void* d_ws, size_t ws_size,
                              hipStream_t stream) {
  (void)in_sizes; (void)n_in; (void)out_size; (void)ws_size;
  const float* x = (const float*)d_in[0];      // (2,4096,1024) fp32
  const float* gum = (const float*)d_in[1];    // (16,64,64) fp32
  const float* wqkv = (const float*)d_in[2];   // (1024,3072) fp32
  const float* sortw = (const float*)d_in[3];  // (1,8,256,64) fp32
  const float* wout = (const float*)d_in[4];   // (1024,1024) fp32
  const float* bout = (const float*)d_in[5];   // (1024,) fp32
  float* out = (float*)d_out;                  // (2,4096,1024) fp32

  char* ws = (char*)d_ws;
  size_t off = 0;
  auto alloc = [&](size_t bytes) {
    char* p = ws + off;
    off += (bytes + 255) & ~(size_t)255;
    return p;
  };
  ushort* xb = (ushort*)alloc((size_t)8192 * 1024 * 2);
  float* xsum2 = (float*)alloc((size_t)256 * 1024 * 4);
  ushort* wqkvT = (ushort*)alloc((size_t)3072 * 1024 * 2);
  ushort* woutT = (ushort*)alloc((size_t)1024 * 1024 * 2);
  float* SX = (float*)alloc((size_t)16 * 256 * 64 * 4);
  ushort* Qb = (ushort*)alloc((size_t)16 * 64 * 64 * 128 * 2);
  ushort* Kb = (ushort*)alloc((size_t)16 * 64 * 64 * 128 * 2);
  ushort* VT = (ushort*)alloc((size_t)16 * 64 * 128 * 64 * 2);
  int* idxArr = (int*)alloc((size_t)16 * 64 * 4);
  float* wgtArr = (float*)alloc((size_t)16 * 64 * 4);
  ushort* attn = xb;        // alias: xb dead after qkv gemm
  float* SXP = (float*)Qb;  // alias: 8 MB partials, dead before Qb written

  prep_x<<<256, 256, 0, stream>>>(x, xb, xsum2);
  transpose_f2b<<<dim3(3072 / 32, 1024 / 32), 256, 0, stream>>>(wqkv, wqkvT, 1024, 3072);
  transpose_f2b<<<dim3(1024 / 32, 1024 / 32), 256, 0, stream>>>(wout, woutT, 1024, 1024);
  sx_gemm_partial<<<dim3(8, 16, 8), 256, 0, stream>>>(xsum2, wqkv, SXP);
  sx_reduce<<<dim3(8, 128), 256, 0, stream>>>(SXP, SX);
  sortnet_sinkhorn<<<16, 256, 0, stream>>>(SX, sortw, gum, idxArr, wgtArr);
  gemm_bt<<<dim3(3072 / 128, 8192 / 128), 256, 0, stream>>>(
      xb, wqkvT, 8192, 3072, 1024, 1, nullptr, nullptr, Qb, Kb, VT);
  attn_kernel<<<16 * 64, 256, 0, stream>>>(Qb, Kb, VT, idxArr, wgtArr, attn);
  gemm_bt<<<dim3(1024 / 128, 8192 / 128), 256, 0, stream>>>(
      attn, woutT, 8192, 1024, 1024, 0, bout, out, nullptr, nullptr, nullptr);
}